// Round 14
// baseline (1110.757 us; speedup 1.0000x reference)
//
#include <hip/hip_runtime.h>
#include <hip/hip_bf16.h>

// MultiTokenPrediction: main head logits + fused CE for main + 2 aux heads.
// B=1, S=2048, D=1024, V=50257, heads predict t+1 (main), t+2, t+3 (aux).

typedef __hip_bfloat16 bf16;
typedef __attribute__((ext_vector_type(8))) short bf16x8;
typedef __attribute__((ext_vector_type(4))) float f32x4;

typedef const __attribute__((address_space(1))) void* gptr_t;
typedef __attribute__((address_space(3))) void* lptr_t;

#define S_LEN   2048
#define DMODEL  1024
#define VOCAB   50257
#define NPADR   50304   // 393*128 padded rows for Wb
#define NT128   393
#define NBLK    6288    // 8*49*16 + 16
#define NCVT    1576    // cvt-role blocks (1572 active; 1576 keeps %8==0)

__device__ __forceinline__ void gload_lds16(const void* g, void* l) {
  __builtin_amdgcn_global_load_lds((gptr_t)g, (lptr_t)l, 16, 0, 0);
}

// ---------------- f32 -> bf16 conversion with row zero-padding ----------------
__global__ __launch_bounds__(256) void k_cvt(const float* __restrict__ src,
                                             bf16* __restrict__ dst,
                                             long rows_src, long rows_pad) {
  const long total4 = rows_pad << 8;
  for (long i = (long)blockIdx.x * 256 + threadIdx.x; i < total4;
       i += (long)gridDim.x * 256) {
    const long e = i << 2;
    const long row = e >> 10;
    alignas(8) bf16 o[4];
    if (row < rows_src) {
      const float4 v = *(const float4*)(src + e);
      o[0] = __float2bfloat16(v.x); o[1] = __float2bfloat16(v.y);
      o[2] = __float2bfloat16(v.z); o[3] = __float2bfloat16(v.w);
    } else {
      o[0] = o[1] = o[2] = o[3] = __float2bfloat16(0.f);
    }
    *(uint2*)(dst + e) = *(const uint2*)o;
  }
}

// ------- fused prep: hidden f32 -> hb bf16 AND rmsnorm(hidden)*w -> xn bf16 -------
__global__ __launch_bounds__(256) void k_prep(const float* __restrict__ x,
                                              const float* __restrict__ w,
                                              bf16* __restrict__ hb,
                                              bf16* __restrict__ xn) {
  const int row = blockIdx.x;
  const int t = threadIdx.x;
  const float4 v = ((const float4*)(x + (size_t)row * DMODEL))[t];
  alignas(8) bf16 h[4];
  h[0] = __float2bfloat16(v.x); h[1] = __float2bfloat16(v.y);
  h[2] = __float2bfloat16(v.z); h[3] = __float2bfloat16(v.w);
  *(uint2*)(hb + (size_t)row * DMODEL + t * 4) = *(const uint2*)h;
  float ss = v.x*v.x + v.y*v.y + v.z*v.z + v.w*v.w;
  #pragma unroll
  for (int d = 1; d < 64; d <<= 1) ss += __shfl_xor(ss, d, 64);
  __shared__ float red[4];
  if ((t & 63) == 0) red[t >> 6] = ss;
  __syncthreads();
  const float tot = red[0] + red[1] + red[2] + red[3];
  const float scale = rsqrtf(tot * (1.f / DMODEL) + 1e-5f);
  const float4 wv = ((const float4*)w)[t];
  alignas(8) bf16 o[4];
  o[0] = __float2bfloat16(v.x * scale * wv.x);
  o[1] = __float2bfloat16(v.y * scale * wv.y);
  o[2] = __float2bfloat16(v.z * scale * wv.z);
  o[3] = __float2bfloat16(v.w * scale * wv.w);
  *(uint2*)(xn + (size_t)row * DMODEL + t * 4) = *(const uint2*)o;
}

// ---------------- RMSNorm row kernel: f32 in, bf16 out ----------------
__global__ __launch_bounds__(256) void k_rms(const float* __restrict__ x,
                                             const float* __restrict__ w,
                                             bf16* __restrict__ xn) {
  const int row = blockIdx.x;
  const int t = threadIdx.x;
  const float4 v = ((const float4*)(x + (size_t)row * DMODEL))[t];
  float ss = v.x*v.x + v.y*v.y + v.z*v.z + v.w*v.w;
  #pragma unroll
  for (int d = 1; d < 64; d <<= 1) ss += __shfl_xor(ss, d, 64);
  __shared__ float red[4];
  if ((t & 63) == 0) red[t >> 6] = ss;
  __syncthreads();
  const float tot = red[0] + red[1] + red[2] + red[3];
  const float scale = rsqrtf(tot * (1.f / DMODEL) + 1e-5f);
  const float4 wv = ((const float4*)w)[t];
  alignas(8) bf16 o[4];
  o[0] = __float2bfloat16(v.x * scale * wv.x);
  o[1] = __float2bfloat16(v.y * scale * wv.y);
  o[2] = __float2bfloat16(v.z * scale * wv.z);
  o[3] = __float2bfloat16(v.w * scale * wv.w);
  *(uint2*)(xn + (size_t)row * DMODEL + t * 4) = *(const uint2*)o;
}

// ======== 128x128 bf16 MFMA GEMM (R13 winner) + optional co-scheduled cvt role ========
// C[m][n] = sum_k A[m][k]*B[n][k]. A:[2048][1024], B:[NPADR][1024] bf16.
// BK=64 (16 steps x 32 MFMA), grid NBLK with non-uniform XCD map, st_16x32
// swizzle both-sides (conflicts=0), plain C stores (L2 merges partial lines).
// DO_CVT: leading NCVT blocks (ids 0..1575; 1572 active) convert the NEXT
// head's W f32->bf16 into nextWb CONCURRENTLY with this GEMM -- they fill
// wave-slots the GEMM leaves free (occupancy 42%) and HBM BW it doesn't use
// (2.4 of 6.3 TB/s). Unlike R6's serial per-block tail, these run from
// dispatch onward. NCVT%8==0 keeps the GEMM XCD decode aligned (gid=id-NCVT).
template<bool WRITE_OUT, bool DO_CVT>
__global__ __launch_bounds__(256, 2)
void k_gemm128(const bf16* __restrict__ A, const bf16* __restrict__ B,
               float* __restrict__ C, long ldc, int Nvalid,
               const int* __restrict__ targets, int shift,
               float* __restrict__ pmax, float* __restrict__ psum,
               float* __restrict__ ptgt, int ntiles,
               const float* __restrict__ nextW, bf16* __restrict__ nextWb) {
  __shared__ bf16 As[2][128 * 32];   // k-half 0 / 1, each 8 subtiles of [16][32]
  __shared__ bf16 Bs[2][128 * 32];
  __shared__ float lds_m[128][2];
  __shared__ float lds_s[128][2];
  __shared__ int lds_tgt[128];

  if constexpr (DO_CVT) {
    if (blockIdx.x < NCVT) {
      // cvt role: 32 rows per block, fully coalesced (k_cvt inner loop, block-local)
      const long base = (long)blockIdx.x * 8192;   // float4 index
      for (long i = base + threadIdx.x; i < base + 8192; i += 256) {
        const long e = i << 2;
        const long row = e >> 10;
        if (row >= NPADR) break;
        alignas(8) bf16 o[4];
        if (row < VOCAB) {
          const float4 v = *(const float4*)(nextW + e);
          o[0] = __float2bfloat16(v.x); o[1] = __float2bfloat16(v.y);
          o[2] = __float2bfloat16(v.z); o[3] = __float2bfloat16(v.w);
        } else {
          o[0] = o[1] = o[2] = o[3] = __float2bfloat16(0.f);
        }
        *(uint2*)(nextWb + e) = *(const uint2*)o;
      }
      return;
    }
  }

  const int t = threadIdx.x;
  const int w = t >> 6, l = t & 63, g = l >> 4, q = l & 15;
  const int wr = w >> 1, wc = w & 1;
  const int id = blockIdx.x - (DO_CVT ? NCVT : 0);
  int bm, bn;
  if (id < 6272) {
    const int x = id & 7, u = id >> 3;
    bm = u & 15;
    bn = x * 49 + (u >> 4);
  } else {
    bm = id - 6272;
    bn = 392;
  }

  f32x4 acc[4][4];
  #pragma unroll
  for (int i = 0; i < 4; ++i)
    #pragma unroll
    for (int j = 0; j < 4; ++j)
      #pragma unroll
      for (int r = 0; r < 4; ++r) acc[i][j][r] = 0.f;

  char* dA = (char*)As + w * 1024;
  char* dB = (char*)Bs + w * 1024;
  const int scol = ((t & 3) * 16) ^ (((t >> 5) & 1) * 32);
  const char* gA0 = (const char*)(A + (size_t)(bm * 128 + (t >> 2)) * DMODEL) + scol;
  const char* gA1 = gA0 + (size_t)64 * DMODEL * 2;
  const char* gB0 = (const char*)(B + (size_t)(bn * 128 + (t >> 2)) * DMODEL) + scol;
  const char* gB1 = gB0 + (size_t)64 * DMODEL * 2;

  const int laneoff = (q * 64 + g * 16) ^ (((q >> 3) & 1) << 5);
  const char* rdA = (const char*)As + wr * 4096 + laneoff;
  const char* rdB = (const char*)Bs + wc * 4096 + laneoff;

  for (int k0 = 0; k0 < 16; ++k0) {
    const int kb = k0 * 128;
    gload_lds16(gA0 + kb, dA);
    gload_lds16(gA1 + kb, dA + 4096);
    gload_lds16(gA0 + kb + 64, dA + 8192);
    gload_lds16(gA1 + kb + 64, dA + 12288);
    gload_lds16(gB0 + kb, dB);
    gload_lds16(gB1 + kb, dB + 4096);
    gload_lds16(gB0 + kb + 64, dB + 8192);
    gload_lds16(gB1 + kb + 64, dB + 12288);
    __syncthreads();
    bf16x8 a[4], b[4];
    #pragma unroll
    for (int mi = 0; mi < 4; ++mi) a[mi] = *(const bf16x8*)(rdA + mi * 1024);
    #pragma unroll
    for (int ni = 0; ni < 4; ++ni) b[ni] = *(const bf16x8*)(rdB + ni * 1024);
    __builtin_amdgcn_s_setprio(1);
    #pragma unroll
    for (int mi = 0; mi < 4; ++mi)
      #pragma unroll
      for (int ni = 0; ni < 4; ++ni)
        acc[mi][ni] = __builtin_amdgcn_mfma_f32_16x16x32_bf16(a[mi], b[ni], acc[mi][ni], 0, 0, 0);
    __builtin_amdgcn_s_setprio(0);
    #pragma unroll
    for (int mi = 0; mi < 4; ++mi) a[mi] = *(const bf16x8*)(rdA + 8192 + mi * 1024);
    #pragma unroll
    for (int ni = 0; ni < 4; ++ni) b[ni] = *(const bf16x8*)(rdB + 8192 + ni * 1024);
    __builtin_amdgcn_s_setprio(1);
    #pragma unroll
    for (int mi = 0; mi < 4; ++mi)
      #pragma unroll
      for (int ni = 0; ni < 4; ++ni)
        acc[mi][ni] = __builtin_amdgcn_mfma_f32_16x16x32_bf16(a[mi], b[ni], acc[mi][ni], 0, 0, 0);
    __builtin_amdgcn_s_setprio(0);
    __syncthreads();
  }

  // ---------------- epilogue: C write (plain stores; L2 merges partials) ----------------
  if constexpr (WRITE_OUT) {
    #pragma unroll
    for (int mi = 0; mi < 4; ++mi) {
      #pragma unroll
      for (int r = 0; r < 4; ++r) {
        const long row = bm * 128 + wr * 64 + mi * 16 + g * 4 + r;
        #pragma unroll
        for (int ni = 0; ni < 4; ++ni) {
          const int col = bn * 128 + wc * 64 + ni * 16 + q;
          if (col < Nvalid) C[row * ldc + col] = acc[mi][ni][r];
        }
      }
    }
  }

  // ---------------- fused CE partials ----------------
  if (t < 128) {
    const int rowg = bm * 128 + t;
    lds_tgt[t] = (rowg < S_LEN - shift) ? targets[rowg + shift] : -1;
  }
  __syncthreads();
  #pragma unroll
  for (int mi = 0; mi < 4; ++mi) {
    #pragma unroll
    for (int r = 0; r < 4; ++r) {
      const int rl = wr * 64 + mi * 16 + g * 4 + r;
      const int tgt = lds_tgt[rl];
      float v[4];
      #pragma unroll
      for (int ni = 0; ni < 4; ++ni) {
        const int n = bn * 128 + wc * 64 + ni * 16 + q;
        const float av = acc[mi][ni][r];
        if (n == tgt) ptgt[bm * 128 + rl] = av;
        v[ni] = (n < Nvalid) ? av : -1e30f;
      }
      float m = fmaxf(fmaxf(v[0], v[1]), fmaxf(v[2], v[3]));
      #pragma unroll
      for (int d = 1; d < 16; d <<= 1) m = fmaxf(m, __shfl_xor(m, d, 64));
      float s = 0.f;
      #pragma unroll
      for (int ni = 0; ni < 4; ++ni) s += __expf(v[ni] - m);
      #pragma unroll
      for (int d = 1; d < 16; d <<= 1) s += __shfl_xor(s, d, 64);
      if (q == 0) { lds_m[rl][wc] = m; lds_s[rl][wc] = s; }
    }
  }
  __syncthreads();
  if (t < 128) {
    const float m0 = lds_m[t][0], m1 = lds_m[t][1];
    const float s0 = lds_s[t][0], s1 = lds_s[t][1];
    const float M = fmaxf(m0, m1);
    const float Ssum = s0 * __expf(m0 - M) + s1 * __expf(m1 - M);
    const size_t idx = (size_t)(bm * 128 + t) * ntiles + bn;
    pmax[idx] = M;
    psum[idx] = Ssum;
  }
}

// ---------------- 128x128 GEMM (small d->d projection) ----------------
__global__ __launch_bounds__(256, 2)
void k_gemm(const bf16* __restrict__ A, const bf16* __restrict__ B,
            float* __restrict__ C, long ldc, int Nvalid) {
  constexpr int K = DMODEL;
  __shared__ bf16 As[128 * 32];
  __shared__ bf16 Bs[128 * 32];

  const int t = threadIdx.x;
  const int bn = blockIdx.x, bm = blockIdx.y;
  const int w = t >> 6, l = t & 63, g = l >> 4, q = l & 15;
  const int wr = w >> 1, wc = w & 1;

  f32x4 acc[4][4];
  #pragma unroll
  for (int i = 0; i < 4; ++i)
    #pragma unroll
    for (int j = 0; j < 4; ++j)
      #pragma unroll
      for (int r = 0; r < 4; ++r) acc[i][j][r] = 0.f;

  char* lA0 = (char*)As + w * 1024;
  char* lA1 = (char*)As + 4096 + w * 1024;
  char* lB0 = (char*)Bs + w * 1024;
  char* lB1 = (char*)Bs + 4096 + w * 1024;
  const char* gA0 = (const char*)(A + (size_t)(bm * 128 + (t >> 2)) * K) + (t & 3) * 16;
  const char* gA1 = gA0 + (size_t)64 * K * 2;
  const char* gB0 = (const char*)(B + (size_t)(bn * 128 + (t >> 2)) * K) + (t & 3) * 16;
  const char* gB1 = gB0 + (size_t)64 * K * 2;

  for (int k0 = 0; k0 < K; k0 += 32) {
    const int kb = k0 * 2;
    gload_lds16(gA0 + kb, lA0);
    gload_lds16(gA1 + kb, lA1);
    gload_lds16(gB0 + kb, lB0);
    gload_lds16(gB1 + kb, lB1);
    __syncthreads();
    bf16x8 a[4], b[4];
    #pragma unroll
    for (int mi = 0; mi < 4; ++mi)
      a[mi] = *(const bf16x8*)&As[(wr * 64 + mi * 16 + q) * 32 + g * 8];
    #pragma unroll
    for (int ni = 0; ni < 4; ++ni)
      b[ni] = *(const bf16x8*)&Bs[(wc * 64 + ni * 16 + q) * 32 + g * 8];
    #pragma unroll
    for (int mi = 0; mi < 4; ++mi)
      #pragma unroll
      for (int ni = 0; ni < 4; ++ni)
        acc[mi][ni] = __builtin_amdgcn_mfma_f32_16x16x32_bf16(a[mi], b[ni], acc[mi][ni], 0, 0, 0);
    __syncthreads();
  }

  #pragma unroll
  for (int mi = 0; mi < 4; ++mi) {
    #pragma unroll
    for (int r = 0; r < 4; ++r) {
      const long row = bm * 128 + wr * 64 + mi * 16 + g * 4 + r;
      #pragma unroll
      for (int ni = 0; ni < 4; ++ni) {
        const int col = bn * 128 + wc * 64 + ni * 16 + q;
        if (col < Nvalid) C[row * ldc + col] = acc[mi][ni][r];
      }
    }
  }
}

// ---------------- combine per-row partials -> NLL ----------------
__global__ __launch_bounds__(64) void k_combine(const float* __restrict__ pmax,
                                                const float* __restrict__ psum,
                                                const float* __restrict__ ptgt,
                                                float* __restrict__ nll,
                                                int ntiles, int nv) {
  const int r = blockIdx.x;
  const int l = threadIdx.x;
  float M = -1e30f, Ssum = 0.f;
  for (int tl = l; tl < ntiles; tl += 64) {
    const float m = pmax[(size_t)r * ntiles + tl];
    const float s = psum[(size_t)r * ntiles + tl];
    const float nM = fmaxf(M, m);
    Ssum = Ssum * __expf(M - nM) + s * __expf(m - nM);
    M = nM;
  }
  #pragma unroll
  for (int d = 1; d < 64; d <<= 1) {
    const float m2 = __shfl_xor(M, d, 64);
    const float s2 = __shfl_xor(Ssum, d, 64);
    const float nM = fmaxf(M, m2);
    Ssum = Ssum * __expf(M - nM) + s2 * __expf(m2 - nM);
    M = nM;
  }
  if (l == 0) nll[r] = (r < nv) ? (M + logf(Ssum) - ptgt[r]) : 0.f;
}

// ---------------- final loss ----------------
__global__ __launch_bounds__(256) void k_loss(const float* __restrict__ nll,
                                              float* __restrict__ out) {
  __shared__ float sh[256];
  const int t = threadIdx.x;
  float sums[3];
  #pragma unroll
  for (int h = 0; h < 3; ++h) {
    const int nv = 2047 - h;
    float s = 0.f;
    for (int r = t; r < nv; r += 256) s += nll[h * 2048 + r];
    sh[t] = s; __syncthreads();
    for (int off = 128; off > 0; off >>= 1) {
      if (t < off) sh[t] += sh[t + off];
      __syncthreads();
    }
    sums[h] = sh[0]; __syncthreads();
  }
  if (t == 0)
    out[0] = sums[0] / 2047.f + 0.3f * 0.5f * (sums[1] / 2046.f + sums[2] / 2045.f);
}

extern "C" void kernel_launch(void* const* d_in, const int* in_sizes, int n_in,
                              void* d_out, int out_size, void* d_ws, size_t ws_size,
                              hipStream_t stream) {
  const float* hidden      = (const float*)d_in[0];
  const int*   targets     = (const int*)d_in[1];
  const float* emb_w       = (const float*)d_in[2];
  const float* main_norm_w = (const float*)d_in[3];
  const float* aux_proj_w  = (const float*)d_in[4];
  const float* aux_norm_w  = (const float*)d_in[5];
  const float* aux_out_w   = (const float*)d_in[6];
  float* out = (float*)d_out;

  char* ws = (char*)d_ws;
  const size_t WB = 104857600;                     // W buffer stride (103 MB used)
  const bool big = ws_size >= 2 * WB + 27000000;   // ping-pong fits?

  bf16* WbA = (bf16*)(ws);
  bf16* WbB = big ? (bf16*)(ws + WB) : WbA;
  char* rest = ws + (big ? 2 * WB : WB);
  bf16*  hb    = (bf16*)(rest);                    // 4 MiB
  bf16*  xn    = (bf16*)(rest + 4194304);          // 4 MiB
  bf16*  projb = (bf16*)(rest + 8388608);          // 4 MiB
  float* hbuf  = (float*)(rest + 12582912);        // 8 MiB
  float* pmax  = (float*)(rest + 20971520);        // [2048][393]
  float* psum  = (float*)(rest + 24248320);
  float* ptgt  = (float*)(rest + 27525120);
  float* nll   = (float*)(rest + 27533312);

  // prep
  k_prep<<<2048, 256, 0, stream>>>(hidden, main_norm_w, hb, xn);
  k_cvt<<<2048, 256, 0, stream>>>(aux_proj_w, projb, 2048, 2048);
  k_cvt<<<2048, 256, 0, stream>>>(emb_w, WbA, VOCAB, NPADR);

  if (big) {
    // main head: GEMM(WbA) + co-scheduled cvt(aux0 W -> WbB)
    k_gemm128<true, true><<<NBLK + NCVT, 256, 0, stream>>>(
        xn, WbA, out, VOCAB, VOCAB, targets, 1, pmax, psum, ptgt, NT128,
        aux_out_w, WbB);
    k_combine<<<2048, 64, 0, stream>>>(pmax, psum, ptgt, nll, NT128, 2047);

    // aux head 0: GEMM(WbB) + co-scheduled cvt(aux1 W -> WbA)
    k_gemm<<<dim3(8, 16), 256, 0, stream>>>(hb, projb, hbuf, DMODEL, DMODEL);
    k_rms<<<2048, 256, 0, stream>>>(hbuf, aux_norm_w, xn);
    k_gemm128<false, true><<<NBLK + NCVT, 256, 0, stream>>>(
        xn, WbB, nullptr, 0, VOCAB, targets, 2, pmax, psum, ptgt, NT128,
        aux_out_w + (size_t)VOCAB * DMODEL, WbA);
    k_combine<<<2048, 64, 0, stream>>>(pmax, psum, ptgt, nll + 2048, NT128, 2046);

    // aux head 1: GEMM(WbA), no cvt role
    k_gemm<<<dim3(8, 16), 256, 0, stream>>>(
        hb, projb + (size_t)DMODEL * DMODEL, hbuf, DMODEL, DMODEL);
    k_rms<<<2048, 256, 0, stream>>>(hbuf, aux_norm_w + DMODEL, xn);
    k_gemm128<false, false><<<NBLK, 256, 0, stream>>>(
        xn, WbA, nullptr, 0, VOCAB, targets, 3, pmax, psum, ptgt, NT128,
        nullptr, nullptr);
    k_combine<<<2048, 64, 0, stream>>>(pmax, psum, ptgt, nll + 2 * 2048, NT128, 2045);
  } else {
    // fallback: R13 flow (single W buffer, explicit cvt per head)
    k_gemm128<true, false><<<NBLK, 256, 0, stream>>>(
        xn, WbA, out, VOCAB, VOCAB, targets, 1, pmax, psum, ptgt, NT128,
        nullptr, nullptr);
    k_combine<<<2048, 64, 0, stream>>>(pmax, psum, ptgt, nll, NT128, 2047);
    for (int i = 0; i < 2; ++i) {
      k_cvt<<<2048, 256, 0, stream>>>(aux_out_w + (size_t)i * VOCAB * DMODEL, WbA, VOCAB, NPADR);
      k_gemm<<<dim3(8, 16), 256, 0, stream>>>(
          hb, projb + (size_t)i * DMODEL * DMODEL, hbuf, DMODEL, DMODEL);
      k_rms<<<2048, 256, 0, stream>>>(hbuf, aux_norm_w + (size_t)i * DMODEL, xn);
      k_gemm128<false, false><<<NBLK, 256, 0, stream>>>(
          xn, WbA, nullptr, 0, VOCAB, targets, i + 2, pmax, psum, ptgt, NT128,
          nullptr, nullptr);
      k_combine<<<2048, 64, 0, stream>>>(pmax, psum, ptgt, nll + (i + 1) * 2048, NT128, 2048 - (i + 2));
    }
  }

  k_loss<<<1, 256, 0, stream>>>(nll, out + (size_t)S_LEN * VOCAB);
}

// Round 15
// 1086.325 us; speedup vs baseline: 1.0225x; 1.0225x over previous
//
#include <hip/hip_runtime.h>
#include <hip/hip_bf16.h>

// MultiTokenPrediction: main head logits + fused CE for main + 2 aux heads.
// B=1, S=2048, D=1024, V=50257, heads predict t+1 (main), t+2, t+3 (aux).
// FINAL: union of session-verified wins (R10 swizzle+XCD grid, R11 BK=64,
// R13 plain stores + k_prep fusion). Five cvt-fold attempts (R6/R8/R9/R12/
// R14) all showed the W-cvt cost is conserved -- it stays as a standalone
// roofline-speed copy pass.

typedef __hip_bfloat16 bf16;
typedef __attribute__((ext_vector_type(8))) short bf16x8;
typedef __attribute__((ext_vector_type(4))) float f32x4;

typedef const __attribute__((address_space(1))) void* gptr_t;
typedef __attribute__((address_space(3))) void* lptr_t;

#define S_LEN   2048
#define DMODEL  1024
#define VOCAB   50257
#define NPADR   50304   // 393*128 padded rows for Wb
#define NT128   393
#define NBLK    6288    // 8*49*16 + 16

__device__ __forceinline__ void gload_lds16(const void* g, void* l) {
  __builtin_amdgcn_global_load_lds((gptr_t)g, (lptr_t)l, 16, 0, 0);
}

// ---------------- f32 -> bf16 conversion with row zero-padding ----------------
__global__ __launch_bounds__(256) void k_cvt(const float* __restrict__ src,
                                             bf16* __restrict__ dst,
                                             long rows_src, long rows_pad) {
  const long total4 = rows_pad << 8;
  for (long i = (long)blockIdx.x * 256 + threadIdx.x; i < total4;
       i += (long)gridDim.x * 256) {
    const long e = i << 2;
    const long row = e >> 10;
    alignas(8) bf16 o[4];
    if (row < rows_src) {
      const float4 v = *(const float4*)(src + e);
      o[0] = __float2bfloat16(v.x); o[1] = __float2bfloat16(v.y);
      o[2] = __float2bfloat16(v.z); o[3] = __float2bfloat16(v.w);
    } else {
      o[0] = o[1] = o[2] = o[3] = __float2bfloat16(0.f);
    }
    *(uint2*)(dst + e) = *(const uint2*)o;
  }
}

// ------- fused prep: hidden f32 -> hb bf16 AND rmsnorm(hidden)*w -> xn bf16 -------
__global__ __launch_bounds__(256) void k_prep(const float* __restrict__ x,
                                              const float* __restrict__ w,
                                              bf16* __restrict__ hb,
                                              bf16* __restrict__ xn) {
  const int row = blockIdx.x;
  const int t = threadIdx.x;
  const float4 v = ((const float4*)(x + (size_t)row * DMODEL))[t];
  alignas(8) bf16 h[4];
  h[0] = __float2bfloat16(v.x); h[1] = __float2bfloat16(v.y);
  h[2] = __float2bfloat16(v.z); h[3] = __float2bfloat16(v.w);
  *(uint2*)(hb + (size_t)row * DMODEL + t * 4) = *(const uint2*)h;
  float ss = v.x*v.x + v.y*v.y + v.z*v.z + v.w*v.w;
  #pragma unroll
  for (int d = 1; d < 64; d <<= 1) ss += __shfl_xor(ss, d, 64);
  __shared__ float red[4];
  if ((t & 63) == 0) red[t >> 6] = ss;
  __syncthreads();
  const float tot = red[0] + red[1] + red[2] + red[3];
  const float scale = rsqrtf(tot * (1.f / DMODEL) + 1e-5f);
  const float4 wv = ((const float4*)w)[t];
  alignas(8) bf16 o[4];
  o[0] = __float2bfloat16(v.x * scale * wv.x);
  o[1] = __float2bfloat16(v.y * scale * wv.y);
  o[2] = __float2bfloat16(v.z * scale * wv.z);
  o[3] = __float2bfloat16(v.w * scale * wv.w);
  *(uint2*)(xn + (size_t)row * DMODEL + t * 4) = *(const uint2*)o;
}

// ---------------- RMSNorm row kernel: f32 in, bf16 out ----------------
__global__ __launch_bounds__(256) void k_rms(const float* __restrict__ x,
                                             const float* __restrict__ w,
                                             bf16* __restrict__ xn) {
  const int row = blockIdx.x;
  const int t = threadIdx.x;
  const float4 v = ((const float4*)(x + (size_t)row * DMODEL))[t];
  float ss = v.x*v.x + v.y*v.y + v.z*v.z + v.w*v.w;
  #pragma unroll
  for (int d = 1; d < 64; d <<= 1) ss += __shfl_xor(ss, d, 64);
  __shared__ float red[4];
  if ((t & 63) == 0) red[t >> 6] = ss;
  __syncthreads();
  const float tot = red[0] + red[1] + red[2] + red[3];
  const float scale = rsqrtf(tot * (1.f / DMODEL) + 1e-5f);
  const float4 wv = ((const float4*)w)[t];
  alignas(8) bf16 o[4];
  o[0] = __float2bfloat16(v.x * scale * wv.x);
  o[1] = __float2bfloat16(v.y * scale * wv.y);
  o[2] = __float2bfloat16(v.z * scale * wv.z);
  o[3] = __float2bfloat16(v.w * scale * wv.w);
  *(uint2*)(xn + (size_t)row * DMODEL + t * 4) = *(const uint2*)o;
}

// ======== 128x128 bf16 MFMA GEMM (session winner) ========
// C[m][n] = sum_k A[m][k]*B[n][k]. A:[2048][1024], B:[NPADR][1024] bf16.
// BK=64 (16 steps x 32 MFMA, 2 barriers/step). Grid NBLK, non-uniform XCD
// map (ids<6272: xcd=id&7 owns 49 bn x 16 bm consecutive; tail 16 -> bn=392)
// so B tiles are XCD-L2-shared. st_16x32 swizzle both-sides: DMA dest linear,
// source col pre-swizzled, frag-read XORed (conflicts = 0, verified R10/R11).
// Plain C stores (L2 merges partial 64B lines at ldc=50257; nt-store was
// +136MB WRITE, R11 vs R13). CE partials fused in epilogue.
template<bool WRITE_OUT>
__global__ __launch_bounds__(256, 2)
void k_gemm128(const bf16* __restrict__ A, const bf16* __restrict__ B,
               float* __restrict__ C, long ldc, int Nvalid,
               const int* __restrict__ targets, int shift,
               float* __restrict__ pmax, float* __restrict__ psum,
               float* __restrict__ ptgt, int ntiles) {
  __shared__ bf16 As[2][128 * 32];   // k-half 0 / 1, each 8 subtiles of [16][32]
  __shared__ bf16 Bs[2][128 * 32];
  __shared__ float lds_m[128][2];
  __shared__ float lds_s[128][2];
  __shared__ int lds_tgt[128];

  const int t = threadIdx.x;
  const int w = t >> 6, l = t & 63, g = l >> 4, q = l & 15;
  const int wr = w >> 1, wc = w & 1;
  const int id = blockIdx.x;
  int bm, bn;
  if (id < 6272) {
    const int x = id & 7, u = id >> 3;
    bm = u & 15;
    bn = x * 49 + (u >> 4);
  } else {
    bm = id - 6272;
    bn = 392;
  }

  f32x4 acc[4][4];
  #pragma unroll
  for (int i = 0; i < 4; ++i)
    #pragma unroll
    for (int j = 0; j < 4; ++j)
      #pragma unroll
      for (int r = 0; r < 4; ++r) acc[i][j][r] = 0.f;

  // staging dests (linear; wave w fills subtiles w and 4+w of each half-array)
  char* dA = (char*)As + w * 1024;
  char* dB = (char*)Bs + w * 1024;
  // global sources, col pre-swizzled (bytes within the 64-byte k-half row)
  const int scol = ((t & 3) * 16) ^ (((t >> 5) & 1) * 32);
  const char* gA0 = (const char*)(A + (size_t)(bm * 128 + (t >> 2)) * DMODEL) + scol;
  const char* gA1 = gA0 + (size_t)64 * DMODEL * 2;
  const char* gB0 = (const char*)(B + (size_t)(bn * 128 + (t >> 2)) * DMODEL) + scol;
  const char* gB1 = gB0 + (size_t)64 * DMODEL * 2;

  // frag-read bases (st_16x32-swizzled; verified conflict-free)
  const int laneoff = (q * 64 + g * 16) ^ (((q >> 3) & 1) << 5);
  const char* rdA = (const char*)As + wr * 4096 + laneoff;
  const char* rdB = (const char*)Bs + wc * 4096 + laneoff;

  for (int k0 = 0; k0 < 16; ++k0) {
    const int kb = k0 * 128;         // byte offset of this 64-col K-step
    gload_lds16(gA0 + kb, dA);
    gload_lds16(gA1 + kb, dA + 4096);
    gload_lds16(gA0 + kb + 64, dA + 8192);
    gload_lds16(gA1 + kb + 64, dA + 12288);
    gload_lds16(gB0 + kb, dB);
    gload_lds16(gB1 + kb, dB + 4096);
    gload_lds16(gB0 + kb + 64, dB + 8192);
    gload_lds16(gB1 + kb + 64, dB + 12288);
    __syncthreads();
    bf16x8 a[4], b[4];
    // ---- k-half 0 ----
    #pragma unroll
    for (int mi = 0; mi < 4; ++mi) a[mi] = *(const bf16x8*)(rdA + mi * 1024);
    #pragma unroll
    for (int ni = 0; ni < 4; ++ni) b[ni] = *(const bf16x8*)(rdB + ni * 1024);
    __builtin_amdgcn_s_setprio(1);
    #pragma unroll
    for (int mi = 0; mi < 4; ++mi)
      #pragma unroll
      for (int ni = 0; ni < 4; ++ni)
        acc[mi][ni] = __builtin_amdgcn_mfma_f32_16x16x32_bf16(a[mi], b[ni], acc[mi][ni], 0, 0, 0);
    __builtin_amdgcn_s_setprio(0);
    // ---- k-half 1 ----
    #pragma unroll
    for (int mi = 0; mi < 4; ++mi) a[mi] = *(const bf16x8*)(rdA + 8192 + mi * 1024);
    #pragma unroll
    for (int ni = 0; ni < 4; ++ni) b[ni] = *(const bf16x8*)(rdB + 8192 + ni * 1024);
    __builtin_amdgcn_s_setprio(1);
    #pragma unroll
    for (int mi = 0; mi < 4; ++mi)
      #pragma unroll
      for (int ni = 0; ni < 4; ++ni)
        acc[mi][ni] = __builtin_amdgcn_mfma_f32_16x16x32_bf16(a[mi], b[ni], acc[mi][ni], 0, 0, 0);
    __builtin_amdgcn_s_setprio(0);
    __syncthreads();
  }

  // ---------------- epilogue: C write (plain stores; L2 merges partials) ----------------
  if constexpr (WRITE_OUT) {
    #pragma unroll
    for (int mi = 0; mi < 4; ++mi) {
      #pragma unroll
      for (int r = 0; r < 4; ++r) {
        const long row = bm * 128 + wr * 64 + mi * 16 + g * 4 + r;
        #pragma unroll
        for (int ni = 0; ni < 4; ++ni) {
          const int col = bn * 128 + wc * 64 + ni * 16 + q;
          if (col < Nvalid) C[row * ldc + col] = acc[mi][ni][r];
        }
      }
    }
  }

  // ---------------- fused CE partials ----------------
  if (t < 128) {
    const int rowg = bm * 128 + t;
    lds_tgt[t] = (rowg < S_LEN - shift) ? targets[rowg + shift] : -1;
  }
  __syncthreads();
  #pragma unroll
  for (int mi = 0; mi < 4; ++mi) {
    #pragma unroll
    for (int r = 0; r < 4; ++r) {
      const int rl = wr * 64 + mi * 16 + g * 4 + r;
      const int tgt = lds_tgt[rl];
      float v[4];
      #pragma unroll
      for (int ni = 0; ni < 4; ++ni) {
        const int n = bn * 128 + wc * 64 + ni * 16 + q;
        const float av = acc[mi][ni][r];
        if (n == tgt) ptgt[bm * 128 + rl] = av;
        v[ni] = (n < Nvalid) ? av : -1e30f;
      }
      float m = fmaxf(fmaxf(v[0], v[1]), fmaxf(v[2], v[3]));
      #pragma unroll
      for (int d = 1; d < 16; d <<= 1) m = fmaxf(m, __shfl_xor(m, d, 64));
      float s = 0.f;
      #pragma unroll
      for (int ni = 0; ni < 4; ++ni) s += __expf(v[ni] - m);
      #pragma unroll
      for (int d = 1; d < 16; d <<= 1) s += __shfl_xor(s, d, 64);
      if (q == 0) { lds_m[rl][wc] = m; lds_s[rl][wc] = s; }
    }
  }
  __syncthreads();
  if (t < 128) {
    const float m0 = lds_m[t][0], m1 = lds_m[t][1];
    const float s0 = lds_s[t][0], s1 = lds_s[t][1];
    const float M = fmaxf(m0, m1);
    const float Ssum = s0 * __expf(m0 - M) + s1 * __expf(m1 - M);
    const size_t idx = (size_t)(bm * 128 + t) * ntiles + bn;
    pmax[idx] = M;
    psum[idx] = Ssum;
  }
}

// ---------------- 128x128 GEMM (small d->d projection) ----------------
__global__ __launch_bounds__(256, 2)
void k_gemm(const bf16* __restrict__ A, const bf16* __restrict__ B,
            float* __restrict__ C, long ldc, int Nvalid) {
  constexpr int K = DMODEL;
  __shared__ bf16 As[128 * 32];
  __shared__ bf16 Bs[128 * 32];

  const int t = threadIdx.x;
  const int bn = blockIdx.x, bm = blockIdx.y;
  const int w = t >> 6, l = t & 63, g = l >> 4, q = l & 15;
  const int wr = w >> 1, wc = w & 1;

  f32x4 acc[4][4];
  #pragma unroll
  for (int i = 0; i < 4; ++i)
    #pragma unroll
    for (int j = 0; j < 4; ++j)
      #pragma unroll
      for (int r = 0; r < 4; ++r) acc[i][j][r] = 0.f;

  char* lA0 = (char*)As + w * 1024;
  char* lA1 = (char*)As + 4096 + w * 1024;
  char* lB0 = (char*)Bs + w * 1024;
  char* lB1 = (char*)Bs + 4096 + w * 1024;
  const char* gA0 = (const char*)(A + (size_t)(bm * 128 + (t >> 2)) * K) + (t & 3) * 16;
  const char* gA1 = gA0 + (size_t)64 * K * 2;
  const char* gB0 = (const char*)(B + (size_t)(bn * 128 + (t >> 2)) * K) + (t & 3) * 16;
  const char* gB1 = gB0 + (size_t)64 * K * 2;

  for (int k0 = 0; k0 < K; k0 += 32) {
    const int kb = k0 * 2;
    gload_lds16(gA0 + kb, lA0);
    gload_lds16(gA1 + kb, lA1);
    gload_lds16(gB0 + kb, lB0);
    gload_lds16(gB1 + kb, lB1);
    __syncthreads();
    bf16x8 a[4], b[4];
    #pragma unroll
    for (int mi = 0; mi < 4; ++mi)
      a[mi] = *(const bf16x8*)&As[(wr * 64 + mi * 16 + q) * 32 + g * 8];
    #pragma unroll
    for (int ni = 0; ni < 4; ++ni)
      b[ni] = *(const bf16x8*)&Bs[(wc * 64 + ni * 16 + q) * 32 + g * 8];
    #pragma unroll
    for (int mi = 0; mi < 4; ++mi)
      #pragma unroll
      for (int ni = 0; ni < 4; ++ni)
        acc[mi][ni] = __builtin_amdgcn_mfma_f32_16x16x32_bf16(a[mi], b[ni], acc[mi][ni], 0, 0, 0);
    __syncthreads();
  }

  #pragma unroll
  for (int mi = 0; mi < 4; ++mi) {
    #pragma unroll
    for (int r = 0; r < 4; ++r) {
      const long row = bm * 128 + wr * 64 + mi * 16 + g * 4 + r;
      #pragma unroll
      for (int ni = 0; ni < 4; ++ni) {
        const int col = bn * 128 + wc * 64 + ni * 16 + q;
        if (col < Nvalid) C[row * ldc + col] = acc[mi][ni][r];
      }
    }
  }
}

// ---------------- combine per-row partials -> NLL ----------------
__global__ __launch_bounds__(64) void k_combine(const float* __restrict__ pmax,
                                                const float* __restrict__ psum,
                                                const float* __restrict__ ptgt,
                                                float* __restrict__ nll,
                                                int ntiles, int nv) {
  const int r = blockIdx.x;
  const int l = threadIdx.x;
  float M = -1e30f, Ssum = 0.f;
  for (int tl = l; tl < ntiles; tl += 64) {
    const float m = pmax[(size_t)r * ntiles + tl];
    const float s = psum[(size_t)r * ntiles + tl];
    const float nM = fmaxf(M, m);
    Ssum = Ssum * __expf(M - nM) + s * __expf(m - nM);
    M = nM;
  }
  #pragma unroll
  for (int d = 1; d < 64; d <<= 1) {
    const float m2 = __shfl_xor(M, d, 64);
    const float s2 = __shfl_xor(Ssum, d, 64);
    const float nM = fmaxf(M, m2);
    Ssum = Ssum * __expf(M - nM) + s2 * __expf(m2 - nM);
    M = nM;
  }
  if (l == 0) nll[r] = (r < nv) ? (M + logf(Ssum) - ptgt[r]) : 0.f;
}

// ---------------- final loss ----------------
__global__ __launch_bounds__(256) void k_loss(const float* __restrict__ nll,
                                              float* __restrict__ out) {
  __shared__ float sh[256];
  const int t = threadIdx.x;
  float sums[3];
  #pragma unroll
  for (int h = 0; h < 3; ++h) {
    const int nv = 2047 - h;
    float s = 0.f;
    for (int r = t; r < nv; r += 256) s += nll[h * 2048 + r];
    sh[t] = s; __syncthreads();
    for (int off = 128; off > 0; off >>= 1) {
      if (t < off) sh[t] += sh[t + off];
      __syncthreads();
    }
    sums[h] = sh[0]; __syncthreads();
  }
  if (t == 0)
    out[0] = sums[0] / 2047.f + 0.3f * 0.5f * (sums[1] / 2046.f + sums[2] / 2045.f);
}

extern "C" void kernel_launch(void* const* d_in, const int* in_sizes, int n_in,
                              void* d_out, int out_size, void* d_ws, size_t ws_size,
                              hipStream_t stream) {
  const float* hidden      = (const float*)d_in[0];
  const int*   targets     = (const int*)d_in[1];
  const float* emb_w       = (const float*)d_in[2];
  const float* main_norm_w = (const float*)d_in[3];
  const float* aux_proj_w  = (const float*)d_in[4];
  const float* aux_norm_w  = (const float*)d_in[5];
  const float* aux_out_w   = (const float*)d_in[6];
  float* out = (float*)d_out;

  char* ws = (char*)d_ws;
  bf16*  Wb    = (bf16*)(ws);                   // [NPADR][1024] bf16, 103,022,592 B
  bf16*  hb    = (bf16*)(ws + 104857600);       // hidden bf16, 4 MiB
  bf16*  xn    = (bf16*)(ws + 109051904);       // normalized input bf16, 4 MiB
  bf16*  projb = (bf16*)(ws + 113246208);       // aux proj weights bf16, 4 MiB
  float* hbuf  = (float*)(ws + 117440512);      // aux pre-norm f32, 8 MiB
  float* pmax  = (float*)(ws + 125829120);      // [2048][393] f32
  float* psum  = (float*)(ws + 129105920);      // [2048][393] f32
  float* ptgt  = (float*)(ws + 132382720);      // [2048]
  float* nll   = (float*)(ws + 132390912);      // [3][2048]

  // prep: hidden->hb + rmsnorm->xn fused; proj weights cvt
  k_prep<<<2048, 256, 0, stream>>>(hidden, main_norm_w, hb, xn);
  k_cvt<<<2048, 256, 0, stream>>>(aux_proj_w, projb, 2048, 2048);

  // ---- main head ----
  k_cvt<<<2048, 256, 0, stream>>>(emb_w, Wb, VOCAB, NPADR);
  k_gemm128<true><<<NBLK, 256, 0, stream>>>(
      xn, Wb, out, VOCAB, VOCAB, targets, 1, pmax, psum, ptgt, NT128);
  k_combine<<<2048, 64, 0, stream>>>(pmax, psum, ptgt, nll, NT128, 2047);

  // ---- aux heads ----
  for (int i = 0; i < 2; ++i) {
    k_cvt<<<2048, 256, 0, stream>>>(aux_out_w + (size_t)i * VOCAB * DMODEL, Wb, VOCAB, NPADR);
    k_gemm<<<dim3(8, 16), 256, 0, stream>>>(
        hb, projb + (size_t)i * DMODEL * DMODEL, hbuf, DMODEL, DMODEL);
    k_rms<<<2048, 256, 0, stream>>>(hbuf, aux_norm_w + (size_t)i * DMODEL, xn);
    k_gemm128<false><<<NBLK, 256, 0, stream>>>(
        xn, Wb, nullptr, 0, VOCAB, targets, i + 2, pmax, psum, ptgt, NT128);
    k_combine<<<2048, 64, 0, stream>>>(pmax, psum, ptgt, nll + (i + 1) * 2048, NT128, 2048 - (i + 2));
  }

  k_loss<<<1, 256, 0, stream>>>(nll, out + (size_t)S_LEN * VOCAB);
}